// Round 1
// baseline (1401.439 us; speedup 1.0000x reference)
//
#include <hip/hip_runtime.h>
#include <hip/hip_bf16.h>

// Edge_Drop_Learner: w_s = mlp(node_emb), w_d = mlp(node_emb), w_e = mlp(edge_fea)
// gate = (logit(eps) + w_s[src] + w_d[dst] + w_e)/0.5 ; aug = sigmoid(gate)
// out[0] = mean(1-aug), out[1..E] = aug.
// Strategy: bf16 MFMA (16x16x32) for the first layers, f32 epilogue for layer 2.

typedef __attribute__((ext_vector_type(8))) short bf16x8;
typedef __attribute__((ext_vector_type(4))) float f32x4;

#define NNODE 50000
#define NEDGE 1600000
#define BIASC 1e-4f

static __device__ __forceinline__ unsigned short f2bf(float f) {
    unsigned u = __float_as_uint(f);
    return (unsigned short)((u + 0x7fffu + ((u >> 16) & 1u)) >> 16); // RNE
}

static __device__ __forceinline__ bf16x8 cvt8(const float* __restrict__ p) {
    f32x4 a = *reinterpret_cast<const f32x4*>(p);
    f32x4 b = *reinterpret_cast<const f32x4*>(p + 4);
    bf16x8 r;
    r[0] = (short)f2bf(a[0]); r[1] = (short)f2bf(a[1]);
    r[2] = (short)f2bf(a[2]); r[3] = (short)f2bf(a[3]);
    r[4] = (short)f2bf(b[0]); r[5] = (short)f2bf(b[1]);
    r[6] = (short)f2bf(b[2]); r[7] = (short)f2bf(b[3]);
    return r;
}

// ---- prep: W[k][j] f32 -> WT[j][k] bf16 for the three first-layer weights ----
__global__ __launch_bounds__(256) void k_prep(
    const float* __restrict__ w_e1, const float* __restrict__ w_s1,
    const float* __restrict__ w_d1,
    unsigned short* __restrict__ W1eT, unsigned short* __restrict__ WsT,
    unsigned short* __restrict__ WdT)
{
    int t = blockIdx.x * 256 + threadIdx.x;
    if (t < 16384) {                      // edge: K=128, H=128
        int j = t >> 7, k = t & 127;
        W1eT[t] = f2bf(w_e1[k * 128 + j]);
    } else if (t < 16384 + 32768) {       // src: K=256, H=128
        int t2 = t - 16384; int j = t2 >> 8, k = t2 & 255;
        WsT[t2] = f2bf(w_s1[k * 128 + j]);
    } else if (t < 16384 + 65536) {       // dst
        int t2 = t - 49152; int j = t2 >> 8, k = t2 & 255;
        WdT[t2] = f2bf(w_d1[k * 128 + j]);
    }
}

// ---- node kernel: one wave = 16 nodes, both MLPs (A-frags reused) ----
__global__ __launch_bounds__(256) void k_node(
    const float* __restrict__ emb,
    const unsigned short* __restrict__ WsT, const unsigned short* __restrict__ WdT,
    const float* __restrict__ b_s1, const float* __restrict__ w_s2, const float* __restrict__ b_s2,
    const float* __restrict__ b_d1, const float* __restrict__ w_d2, const float* __restrict__ b_d2,
    float* __restrict__ w_s, float* __restrict__ w_d)
{
    const int wid = (blockIdx.x * 256 + threadIdx.x) >> 6;
    if (wid >= NNODE / 16) return;
    const int lane = threadIdx.x & 63;
    const int r = lane & 15, kg = lane >> 4;
    const int n0 = wid * 16;

    // A fragments: lane holds X[n0 + r][32t + 8kg .. +7], t = 0..7 (K=256)
    const float* xrow = emb + (n0 + r) * 256 + kg * 8;
    bf16x8 a[8];
#pragma unroll
    for (int t = 0; t < 8; ++t) a[t] = cvt8(xrow + t * 32);

#pragma unroll 1
    for (int m = 0; m < 2; ++m) {
        const unsigned short* WT = m ? WdT : WsT;
        const float* b1 = m ? b_d1 : b_s1;
        const float* w2 = m ? w_d2 : w_s2;
        const float  b2 = m ? b_d2[0] : b_s2[0];
        float* outp = m ? w_d : w_s;

        f32x4 acc[8];
#pragma unroll
        for (int u = 0; u < 8; ++u) acc[u] = (f32x4){0.f, 0.f, 0.f, 0.f};
#pragma unroll
        for (int u = 0; u < 8; ++u) {
            const unsigned short* wrow = WT + (u * 16 + r) * 256 + kg * 8;
#pragma unroll
            for (int t = 0; t < 8; ++t) {
                bf16x8 bf = *reinterpret_cast<const bf16x8*>(wrow + t * 32);
                acc[u] = __builtin_amdgcn_mfma_f32_16x16x32_bf16(a[t], bf, acc[u], 0, 0, 0);
            }
        }
        // epilogue: h = leaky(acc + b1[j]); y = sum_j h*w2[j] + b2
        // C/D layout: col j = 16u + (lane&15); row i = 4*kg + reg
        float p0 = 0.f, p1 = 0.f, p2 = 0.f, p3 = 0.f;
#pragma unroll
        for (int u = 0; u < 8; ++u) {
            int j = u * 16 + r;
            float b1j = b1[j], w2j = w2[j], h;
            h = acc[u][0] + b1j; h = h > 0.f ? h : 0.01f * h; p0 += h * w2j;
            h = acc[u][1] + b1j; h = h > 0.f ? h : 0.01f * h; p1 += h * w2j;
            h = acc[u][2] + b1j; h = h > 0.f ? h : 0.01f * h; p2 += h * w2j;
            h = acc[u][3] + b1j; h = h > 0.f ? h : 0.01f * h; p3 += h * w2j;
        }
#pragma unroll
        for (int msk = 1; msk < 16; msk <<= 1) {
            p0 += __shfl_xor(p0, msk, 16);
            p1 += __shfl_xor(p1, msk, 16);
            p2 += __shfl_xor(p2, msk, 16);
            p3 += __shfl_xor(p3, msk, 16);
        }
        if (r == 0) {
            int base = n0 + kg * 4;
            outp[base + 0] = p0 + b2;
            outp[base + 1] = p1 + b2;
            outp[base + 2] = p2 + b2;
            outp[base + 3] = p3 + b2;
        }
    }
}

// ---- edge kernel: one wave = 32 edges (2 M-tiles share B-frags) ----
__global__ __launch_bounds__(256) void k_edge(
    const float* __restrict__ fea, const unsigned short* __restrict__ W1eT,
    const float* __restrict__ b1, const float* __restrict__ w2,
    const float* __restrict__ b2p, float* __restrict__ ybuf /* d_out+1 */)
{
    const int wid = (blockIdx.x * 256 + threadIdx.x) >> 6; // 0..49999 exact
    const int lane = threadIdx.x & 63;
    const int r = lane & 15, kg = lane >> 4;
    const int e0 = wid * 32;

    bf16x8 a[2][4];
#pragma unroll
    for (int mt = 0; mt < 2; ++mt) {
        const float* xr = fea + (e0 + mt * 16 + r) * 128 + kg * 8;
#pragma unroll
        for (int t = 0; t < 4; ++t) a[mt][t] = cvt8(xr + t * 32);
    }

    f32x4 acc[2][8];
#pragma unroll
    for (int mt = 0; mt < 2; ++mt)
#pragma unroll
        for (int u = 0; u < 8; ++u) acc[mt][u] = (f32x4){0.f, 0.f, 0.f, 0.f};

#pragma unroll
    for (int u = 0; u < 8; ++u) {
        const unsigned short* wrow = W1eT + (u * 16 + r) * 128 + kg * 8;
#pragma unroll
        for (int t = 0; t < 4; ++t) {
            bf16x8 bf = *reinterpret_cast<const bf16x8*>(wrow + t * 32);
            acc[0][u] = __builtin_amdgcn_mfma_f32_16x16x32_bf16(a[0][t], bf, acc[0][u], 0, 0, 0);
            acc[1][u] = __builtin_amdgcn_mfma_f32_16x16x32_bf16(a[1][t], bf, acc[1][u], 0, 0, 0);
        }
    }

    const float b2 = b2p[0];
#pragma unroll
    for (int mt = 0; mt < 2; ++mt) {
        float p0 = 0.f, p1 = 0.f, p2 = 0.f, p3 = 0.f;
#pragma unroll
        for (int u = 0; u < 8; ++u) {
            int j = u * 16 + r;
            float b1j = b1[j], w2j = w2[j], h;
            h = acc[mt][u][0] + b1j; h = h > 0.f ? h : 0.01f * h; p0 += h * w2j;
            h = acc[mt][u][1] + b1j; h = h > 0.f ? h : 0.01f * h; p1 += h * w2j;
            h = acc[mt][u][2] + b1j; h = h > 0.f ? h : 0.01f * h; p2 += h * w2j;
            h = acc[mt][u][3] + b1j; h = h > 0.f ? h : 0.01f * h; p3 += h * w2j;
        }
#pragma unroll
        for (int msk = 1; msk < 16; msk <<= 1) {
            p0 += __shfl_xor(p0, msk, 16);
            p1 += __shfl_xor(p1, msk, 16);
            p2 += __shfl_xor(p2, msk, 16);
            p3 += __shfl_xor(p3, msk, 16);
        }
        if (r == 0) {
            int base = e0 + mt * 16 + kg * 4;   // d_out+1 is only 4B aligned -> scalar stores
            ybuf[base + 0] = p0 + b2;
            ybuf[base + 1] = p1 + b2;
            ybuf[base + 2] = p2 + b2;
            ybuf[base + 3] = p3 + b2;
        }
    }
}

// ---- final: gate/sigmoid/mean ----
__global__ __launch_bounds__(256) void k_final(
    const float* __restrict__ noise, const int* __restrict__ src, const int* __restrict__ dst,
    const float* __restrict__ w_s, const float* __restrict__ w_d,
    float* __restrict__ out)
{
    __shared__ float sm[4];
    int e = blockIdx.x * 256 + threadIdx.x;   // grid covers E exactly
    float y = out[1 + e];
    float eps = fmaf(noise[e], 2.0f * BIASC - 1.0f, 1.0f - BIASC);
    float g = (logf(eps) - log1pf(-eps) + w_s[src[e]] + w_d[dst[e]] + y) * 2.0f; // /TEMP
    float aug = 1.0f / (1.0f + expf(-g));
    out[1 + e] = aug;
    float part = 1.0f - aug;
#pragma unroll
    for (int msk = 32; msk; msk >>= 1) part += __shfl_xor(part, msk, 64);
    if ((threadIdx.x & 63) == 0) sm[threadIdx.x >> 6] = part;
    __syncthreads();
    if (threadIdx.x == 0) {
        float s = sm[0] + sm[1] + sm[2] + sm[3];
        atomicAdd(out, s * (1.0f / (float)NEDGE));
    }
}

extern "C" void kernel_launch(void* const* d_in, const int* in_sizes, int n_in,
                              void* d_out, int out_size, void* d_ws, size_t ws_size,
                              hipStream_t stream) {
    const float* node_emb = (const float*)d_in[0];
    const float* edge_fea = (const float*)d_in[1];
    const float* noise    = (const float*)d_in[2];
    const int*   src      = (const int*)d_in[3];
    const int*   dst      = (const int*)d_in[4];
    const float* w_src1 = (const float*)d_in[5];
    const float* b_src1 = (const float*)d_in[6];
    const float* w_src2 = (const float*)d_in[7];
    const float* b_src2 = (const float*)d_in[8];
    const float* w_dst1 = (const float*)d_in[9];
    const float* b_dst1 = (const float*)d_in[10];
    const float* w_dst2 = (const float*)d_in[11];
    const float* b_dst2 = (const float*)d_in[12];
    const float* w_edge1 = (const float*)d_in[13];
    const float* b_edge1 = (const float*)d_in[14];
    const float* w_edge2 = (const float*)d_in[15];
    const float* b_edge2 = (const float*)d_in[16];

    char* ws = (char*)d_ws;
    unsigned short* W1eT = (unsigned short*)(ws);            // 32 KB
    unsigned short* WsT  = (unsigned short*)(ws + 32768);    // 64 KB
    unsigned short* WdT  = (unsigned short*)(ws + 98304);    // 64 KB
    float* w_s = (float*)(ws + 163840);                      // 200 KB
    float* w_d = (float*)(ws + 363840);                      // 200 KB
    float* out = (float*)d_out;

    hipMemsetAsync(d_out, 0, sizeof(float), stream);         // out[0] accumulator

    k_prep<<<320, 256, 0, stream>>>(w_edge1, w_src1, w_dst1, W1eT, WsT, WdT);
    k_node<<<(NNODE / 64) + 1, 256, 0, stream>>>(node_emb, WsT, WdT,
                                                 b_src1, w_src2, b_src2,
                                                 b_dst1, w_dst2, b_dst2,
                                                 (float*)(ws + 163840), (float*)(ws + 363840));
    k_edge<<<NEDGE / 128, 256, 0, stream>>>(edge_fea, W1eT, b_edge1, w_edge2, b_edge2, out + 1);
    k_final<<<NEDGE / 256, 256, 0, stream>>>(noise, src, dst, w_s, w_d, out);
}